// Round 1
// baseline (594.188 us; speedup 1.0000x reference)
//
#include <hip/hip_runtime.h>
#include <hip/hip_bf16.h>

// DOMINANT GCN autoencoder on MI355X.
// Pipeline per layer: g = (X @ W) * dis[row]   (fp32 vector GEMM, row-scaled)
//                     out = maybe_relu(dis[n]*(g[n] + sum_{src in N(n)} g[src]) + b)
// Aggregation uses a CSR (by dst) built per call: histogram -> 1-block scan -> fill.
// No atomics in the heavy aggregation path.

// ---------------- CSR build ----------------

__global__ __launch_bounds__(256) void init_int2(int* __restrict__ a,
                                                 int* __restrict__ b, int N) {
    int i = blockIdx.x * 256 + threadIdx.x;
    if (i < N) { a[i] = 0; b[i] = 0; }
}

__global__ __launch_bounds__(256) void hist_deg(const int* __restrict__ dst,
                                                int* __restrict__ deg, int E) {
    int e = blockIdx.x * 256 + threadIdx.x;
    if (e < E) atomicAdd(&deg[dst[e]], 1);
}

// Single-block exclusive scan of deg -> row_ptr; also dis = rsqrt(deg+1).
__global__ __launch_bounds__(1024) void scan_deg(const int* __restrict__ deg,
                                                 int* __restrict__ row_ptr,
                                                 float* __restrict__ dis, int N) {
    __shared__ int sums[1024];
    int t = threadIdx.x;
    int chunk = (N + 1023) / 1024;
    int lo = t * chunk;
    int hi = min(lo + chunk, N);
    int s = 0;
    for (int i = lo; i < hi; ++i) s += deg[i];
    sums[t] = s;
    __syncthreads();
    // Hillis-Steele inclusive scan over 1024 partials
    for (int off = 1; off < 1024; off <<= 1) {
        int v = (t >= off) ? sums[t - off] : 0;
        __syncthreads();
        sums[t] += v;
        __syncthreads();
    }
    int prefix = (t == 0) ? 0 : sums[t - 1];
    for (int i = lo; i < hi; ++i) {
        row_ptr[i] = prefix;
        int d = deg[i];
        prefix += d;
        dis[i] = rsqrtf((float)(d + 1));   // +1 self-loop; always > 0
    }
    if (t == 1023) row_ptr[N] = sums[1023];
}

__global__ __launch_bounds__(256) void fill_csr(const int* __restrict__ src,
                                                const int* __restrict__ dst,
                                                const int* __restrict__ row_ptr,
                                                int* __restrict__ cnt,
                                                int* __restrict__ csr_src, int E) {
    int e = blockIdx.x * 256 + threadIdx.x;
    if (e < E) {
        int d = dst[e];
        int pos = row_ptr[d] + atomicAdd(&cnt[d], 1);
        csr_src[pos] = src[e];
    }
}

// ---------------- GEMM with row-scale epilogue ----------------
// G[r][c] = dis[r] * sum_k A[r][k] * W[k][c]
// Block: 256 threads. Register tile 4 rows x 4 cols per thread.
template <int K, int DOUT>
__global__ __launch_bounds__(256) void gemm_scale(const float* __restrict__ A,
                                                  const float* __restrict__ W,
                                                  const float* __restrict__ dis,
                                                  float* __restrict__ G, int N) {
    constexpr int CG   = DOUT / 4;       // float4 col-groups
    constexpr int RG   = 256 / CG;       // row-groups of 4 rows
    constexpr int ROWS = RG * 4;         // rows per block
    constexpr int LDA  = K + 1;          // pad to break bank aliasing

    __shared__ __align__(16) float a_lds[ROWS * LDA];
    __shared__ __align__(16) float w_lds[K * DOUT];

    int t    = threadIdx.x;
    int row0 = blockIdx.x * ROWS;

    // Stage W (whole matrix, <=32 KB) via float4
    constexpr int WF4 = K * DOUT / 4;
    for (int q = t; q < WF4; q += 256)
        reinterpret_cast<float4*>(w_lds)[q] =
            reinterpret_cast<const float4*>(W)[q];

    // Stage A tile (row-major, padded rows)
    constexpr int AF4 = ROWS * K / 4;
    for (int q = t; q < AF4; q += 256) {
        int r  = q / (K / 4);
        int kc = q % (K / 4);
        float4 v = make_float4(0.f, 0.f, 0.f, 0.f);
        int gr = row0 + r;
        if (gr < N)
            v = reinterpret_cast<const float4*>(A + (size_t)gr * K)[kc];
        float* p = &a_lds[r * LDA + kc * 4];
        p[0] = v.x; p[1] = v.y; p[2] = v.z; p[3] = v.w;
    }
    __syncthreads();

    int c0 = (t % CG) * 4;
    int r0 = (t / CG) * 4;

    float4 acc[4] = {};
#pragma unroll 4
    for (int k = 0; k < K; ++k) {
        float4 w4 = *reinterpret_cast<const float4*>(&w_lds[k * DOUT + c0]);
#pragma unroll
        for (int j = 0; j < 4; ++j) {
            float a = a_lds[(r0 + j) * LDA + k];
            acc[j].x += a * w4.x;
            acc[j].y += a * w4.y;
            acc[j].z += a * w4.z;
            acc[j].w += a * w4.w;
        }
    }

#pragma unroll
    for (int j = 0; j < 4; ++j) {
        int gr = row0 + r0 + j;
        if (gr < N) {
            float s = dis[gr];
            float4 o = acc[j];
            o.x *= s; o.y *= s; o.z *= s; o.w *= s;
            reinterpret_cast<float4*>(G + (size_t)gr * DOUT)[c0 / 4] = o;
        }
    }
}

// ---------------- Aggregation (gather, no atomics) ----------------
// One wave per node; lane = feature (F=D/64 features per lane).
template <int D, bool RELU>
__global__ __launch_bounds__(256) void aggregate(const float* __restrict__ G,
                                                 const int* __restrict__ row_ptr,
                                                 const int* __restrict__ csr_src,
                                                 const float* __restrict__ dis,
                                                 const float* __restrict__ bias,
                                                 float* __restrict__ Out, int N) {
    constexpr int F = D / 64;
    int wave = threadIdx.x >> 6;
    int lane = threadIdx.x & 63;
    int n = blockIdx.x * 4 + wave;
    if (n >= N) return;

    float acc[F];
#pragma unroll
    for (int j = 0; j < F; ++j)
        acc[j] = G[(size_t)n * D + j * 64 + lane];   // self-loop term

    int beg = row_ptr[n];
    int end = row_ptr[n + 1];
    for (int i = beg; i < end; ++i) {
        int s = csr_src[i];
        const float* gs = G + (size_t)s * D;
#pragma unroll
        for (int j = 0; j < F; ++j)
            acc[j] += gs[j * 64 + lane];
    }

    float dn = dis[n];
#pragma unroll
    for (int j = 0; j < F; ++j) {
        float v = dn * acc[j] + bias[j * 64 + lane];
        if (RELU) v = fmaxf(v, 0.f);
        Out[(size_t)n * D + j * 64 + lane] = v;
    }
}

// ---------------- Launch ----------------

extern "C" void kernel_launch(void* const* d_in, const int* in_sizes, int n_in,
                              void* d_out, int out_size, void* d_ws, size_t ws_size,
                              hipStream_t stream) {
    const float* x     = (const float*)d_in[0];
    const int*   edges = (const int*)d_in[1];   // [2, E] row-major
    const float* W1 = (const float*)d_in[2];
    const float* b1 = (const float*)d_in[3];
    const float* W2 = (const float*)d_in[4];
    const float* b2 = (const float*)d_in[5];
    const float* W3 = (const float*)d_in[6];
    const float* b3 = (const float*)d_in[7];
    const float* W4 = (const float*)d_in[8];
    const float* b4 = (const float*)d_in[9];

    const int DIN = 128, DH = 64;
    int N = in_sizes[0] / DIN;
    int E = in_sizes[1] / 2;

    const int* e_src = edges;
    const int* e_dst = edges + E;

    float* out   = (float*)d_out;
    float* x_hat = out;                       // [N,128]
    float* z     = out + (size_t)N * DIN;     // [N,64]

    // Workspace carve-up (256 B aligned)
    char*  ws  = (char*)d_ws;
    size_t off = 0;
    auto carve = [&](size_t bytes) {
        void* p = ws + off;
        off = (off + bytes + 255) & ~(size_t)255;
        return p;
    };
    float* dis     = (float*)carve((size_t)N * 4);
    int*   deg     = (int*)  carve((size_t)N * 4);
    int*   cnt     = (int*)  carve((size_t)N * 4);
    int*   row_ptr = (int*)  carve((size_t)(N + 1) * 4);
    int*   csr_src = (int*)  carve((size_t)E * 4);
    float* g       = (float*)carve((size_t)N * DIN * 4);   // widest layer
    float* act     = (float*)carve((size_t)N * DH * 4);    // reused a1 / a3
    (void)ws_size;

    int nb_n = (N + 255) / 256;
    int nb_e = (E + 255) / 256;
    int nb_agg = (N + 3) / 4;

    // CSR build
    init_int2<<<nb_n, 256, 0, stream>>>(deg, cnt, N);
    hist_deg<<<nb_e, 256, 0, stream>>>(e_dst, deg, E);
    scan_deg<<<1, 1024, 0, stream>>>(deg, row_ptr, dis, N);
    fill_csr<<<nb_e, 256, 0, stream>>>(e_src, e_dst, row_ptr, cnt, csr_src, E);

    // Layer 1: x[N,128] @ W1 -> a1 (relu) in act
    gemm_scale<128, 64><<<(N + 63) / 64, 256, 0, stream>>>(x, W1, dis, g, N);
    aggregate<64, true><<<nb_agg, 256, 0, stream>>>(g, row_ptr, csr_src, dis, b1, act, N);

    // Layer 2: act @ W2 -> z (relu) into d_out
    gemm_scale<64, 64><<<(N + 63) / 64, 256, 0, stream>>>(act, W2, dis, g, N);
    aggregate<64, true><<<nb_agg, 256, 0, stream>>>(g, row_ptr, csr_src, dis, b2, z, N);

    // Layer 3: z @ W3 -> a3 (relu) in act
    gemm_scale<64, 64><<<(N + 63) / 64, 256, 0, stream>>>(z, W3, dis, g, N);
    aggregate<64, true><<<nb_agg, 256, 0, stream>>>(g, row_ptr, csr_src, dis, b3, act, N);

    // Layer 4: act @ W4 -> x_hat (no relu) into d_out
    gemm_scale<64, 128><<<(N + 31) / 32, 256, 0, stream>>>(act, W4, dis, g, N);
    aggregate<128, false><<<nb_agg, 256, 0, stream>>>(g, row_ptr, csr_src, dis, b4, x_hat, N);
}

// Round 2
// 496.590 us; speedup vs baseline: 1.1965x; 1.1965x over previous
//
#include <hip/hip_runtime.h>
#include <hip/hip_bf16.h>

// DOMINANT GCN autoencoder on MI355X.
// R2 change: scan_deg (single-block serial scan, 107us) -> 3-phase parallel scan.
// Everything else unchanged from R1 (594us total).

// ---------------- CSR build ----------------

__global__ __launch_bounds__(256) void init_k(int* __restrict__ deg,
                                              int* __restrict__ cnt,
                                              int Npad, int N) {
    int i = blockIdx.x * 256 + threadIdx.x;
    if (i < Npad) deg[i] = 0;   // zero-padded so scan kernels can vector-load
    if (i < N)    cnt[i] = 0;
}

__global__ __launch_bounds__(256) void hist_deg(const int* __restrict__ dst,
                                                int* __restrict__ deg, int E) {
    int e = blockIdx.x * 256 + threadIdx.x;
    if (e < E) atomicAdd(&deg[dst[e]], 1);
}

// Phase 1: per-block (2048 nodes) sum of deg -> block_sums[b]
__global__ __launch_bounds__(256) void scan_phase1(const int* __restrict__ deg,
                                                   int* __restrict__ block_sums) {
    int b = blockIdx.x, t = threadIdx.x;
    const int4* p = reinterpret_cast<const int4*>(deg + (size_t)b * 2048);
    int4 a = p[t * 2], c = p[t * 2 + 1];
    int s = a.x + a.y + a.z + a.w + c.x + c.y + c.z + c.w;
#pragma unroll
    for (int off = 32; off; off >>= 1) s += __shfl_down(s, off);
    __shared__ int wsum[4];
    if ((t & 63) == 0) wsum[t >> 6] = s;
    __syncthreads();
    if (t == 0) block_sums[b] = wsum[0] + wsum[1] + wsum[2] + wsum[3];
}

// Phase 2: single small block scans <=256 block sums -> exclusive block_off;
// writes row_ptr[N] = total.
__global__ __launch_bounds__(256) void scan_phase2(const int* __restrict__ block_sums,
                                                   int* __restrict__ block_off,
                                                   int* __restrict__ row_ptr,
                                                   int B, int N) {
    __shared__ int s[256];
    int t = threadIdx.x;
    int v = (t < B) ? block_sums[t] : 0;
    s[t] = v;
    __syncthreads();
#pragma unroll
    for (int off = 1; off < 256; off <<= 1) {
        int u = (t >= off) ? s[t - off] : 0;
        __syncthreads();
        s[t] += u;
        __syncthreads();
    }
    if (t < B) block_off[t] = s[t] - v;   // exclusive prefix
    if (t == 255) row_ptr[N] = s[255];    // grand total
}

// Phase 3: per-block exclusive scan of 2048 deg values + block offset
// -> row_ptr[i]; also dis[i] = rsqrt(deg+1).
__global__ __launch_bounds__(256) void scan_phase3(const int* __restrict__ deg,
                                                   const int* __restrict__ block_off,
                                                   int* __restrict__ row_ptr,
                                                   float* __restrict__ dis, int N) {
    int b = blockIdx.x, t = threadIdx.x;
    int base = b * 2048 + t * 8;
    const int4* p = reinterpret_cast<const int4*>(deg + base);
    int4 a = p[0], c = p[1];
    int d[8] = {a.x, a.y, a.z, a.w, c.x, c.y, c.z, c.w};
    int pre[8], s = 0;
#pragma unroll
    for (int j = 0; j < 8; ++j) { pre[j] = s; s += d[j]; }
    __shared__ int ls[256];
    ls[t] = s;
    __syncthreads();
#pragma unroll
    for (int off = 1; off < 256; off <<= 1) {
        int u = (t >= off) ? ls[t - off] : 0;
        __syncthreads();
        ls[t] += u;
        __syncthreads();
    }
    int excl = ls[t] - s + block_off[b];
#pragma unroll
    for (int j = 0; j < 8; ++j) {
        int i = base + j;
        if (i < N) {
            row_ptr[i] = excl + pre[j];
            dis[i] = rsqrtf((float)(d[j] + 1));   // +1 self-loop; always > 0
        }
    }
}

__global__ __launch_bounds__(256) void fill_csr(const int* __restrict__ src,
                                                const int* __restrict__ dst,
                                                const int* __restrict__ row_ptr,
                                                int* __restrict__ cnt,
                                                int* __restrict__ csr_src, int E) {
    int e = blockIdx.x * 256 + threadIdx.x;
    if (e < E) {
        int d = dst[e];
        int pos = row_ptr[d] + atomicAdd(&cnt[d], 1);
        csr_src[pos] = src[e];
    }
}

// ---------------- GEMM with row-scale epilogue ----------------
// G[r][c] = dis[r] * sum_k A[r][k] * W[k][c]
template <int K, int DOUT>
__global__ __launch_bounds__(256) void gemm_scale(const float* __restrict__ A,
                                                  const float* __restrict__ W,
                                                  const float* __restrict__ dis,
                                                  float* __restrict__ G, int N) {
    constexpr int CG   = DOUT / 4;
    constexpr int RG   = 256 / CG;
    constexpr int ROWS = RG * 4;
    constexpr int LDA  = K + 1;

    __shared__ __align__(16) float a_lds[ROWS * LDA];
    __shared__ __align__(16) float w_lds[K * DOUT];

    int t    = threadIdx.x;
    int row0 = blockIdx.x * ROWS;

    constexpr int WF4 = K * DOUT / 4;
    for (int q = t; q < WF4; q += 256)
        reinterpret_cast<float4*>(w_lds)[q] =
            reinterpret_cast<const float4*>(W)[q];

    constexpr int AF4 = ROWS * K / 4;
    for (int q = t; q < AF4; q += 256) {
        int r  = q / (K / 4);
        int kc = q % (K / 4);
        float4 v = make_float4(0.f, 0.f, 0.f, 0.f);
        int gr = row0 + r;
        if (gr < N)
            v = reinterpret_cast<const float4*>(A + (size_t)gr * K)[kc];
        float* p = &a_lds[r * LDA + kc * 4];
        p[0] = v.x; p[1] = v.y; p[2] = v.z; p[3] = v.w;
    }
    __syncthreads();

    int c0 = (t % CG) * 4;
    int r0 = (t / CG) * 4;

    float4 acc[4] = {};
#pragma unroll 4
    for (int k = 0; k < K; ++k) {
        float4 w4 = *reinterpret_cast<const float4*>(&w_lds[k * DOUT + c0]);
#pragma unroll
        for (int j = 0; j < 4; ++j) {
            float a = a_lds[(r0 + j) * LDA + k];
            acc[j].x += a * w4.x;
            acc[j].y += a * w4.y;
            acc[j].z += a * w4.z;
            acc[j].w += a * w4.w;
        }
    }

#pragma unroll
    for (int j = 0; j < 4; ++j) {
        int gr = row0 + r0 + j;
        if (gr < N) {
            float s = dis[gr];
            float4 o = acc[j];
            o.x *= s; o.y *= s; o.z *= s; o.w *= s;
            reinterpret_cast<float4*>(G + (size_t)gr * DOUT)[c0 / 4] = o;
        }
    }
}

// ---------------- Aggregation (gather, no atomics) ----------------
template <int D, bool RELU>
__global__ __launch_bounds__(256) void aggregate(const float* __restrict__ G,
                                                 const int* __restrict__ row_ptr,
                                                 const int* __restrict__ csr_src,
                                                 const float* __restrict__ dis,
                                                 const float* __restrict__ bias,
                                                 float* __restrict__ Out, int N) {
    constexpr int F = D / 64;
    int wave = threadIdx.x >> 6;
    int lane = threadIdx.x & 63;
    int n = blockIdx.x * 4 + wave;
    if (n >= N) return;

    float acc[F];
#pragma unroll
    for (int j = 0; j < F; ++j)
        acc[j] = G[(size_t)n * D + j * 64 + lane];   // self-loop term

    int beg = row_ptr[n];
    int end = row_ptr[n + 1];
    for (int i = beg; i < end; ++i) {
        int s = csr_src[i];
        const float* gs = G + (size_t)s * D;
#pragma unroll
        for (int j = 0; j < F; ++j)
            acc[j] += gs[j * 64 + lane];
    }

    float dn = dis[n];
#pragma unroll
    for (int j = 0; j < F; ++j) {
        float v = dn * acc[j] + bias[j * 64 + lane];
        if (RELU) v = fmaxf(v, 0.f);
        Out[(size_t)n * D + j * 64 + lane] = v;
    }
}

// ---------------- Launch ----------------

extern "C" void kernel_launch(void* const* d_in, const int* in_sizes, int n_in,
                              void* d_out, int out_size, void* d_ws, size_t ws_size,
                              hipStream_t stream) {
    const float* x     = (const float*)d_in[0];
    const int*   edges = (const int*)d_in[1];   // [2, E] row-major
    const float* W1 = (const float*)d_in[2];
    const float* b1 = (const float*)d_in[3];
    const float* W2 = (const float*)d_in[4];
    const float* b2 = (const float*)d_in[5];
    const float* W3 = (const float*)d_in[6];
    const float* b3 = (const float*)d_in[7];
    const float* W4 = (const float*)d_in[8];
    const float* b4 = (const float*)d_in[9];

    const int DIN = 128, DH = 64;
    int N = in_sizes[0] / DIN;
    int E = in_sizes[1] / 2;

    const int* e_src = edges;
    const int* e_dst = edges + E;

    float* out   = (float*)d_out;
    float* x_hat = out;                       // [N,128]
    float* z     = out + (size_t)N * DIN;     // [N,64]

    int B    = (N + 2047) / 2048;             // scan blocks (<=256 assumed)
    int Npad = B * 2048;

    char*  ws  = (char*)d_ws;
    size_t off = 0;
    auto carve = [&](size_t bytes) {
        void* p = ws + off;
        off = (off + bytes + 255) & ~(size_t)255;
        return p;
    };
    float* dis        = (float*)carve((size_t)N * 4);
    int*   deg        = (int*)  carve((size_t)Npad * 4);
    int*   cnt        = (int*)  carve((size_t)N * 4);
    int*   row_ptr    = (int*)  carve((size_t)(N + 1) * 4);
    int*   csr_src    = (int*)  carve((size_t)E * 4);
    int*   block_sums = (int*)  carve((size_t)B * 4);
    int*   block_off  = (int*)  carve((size_t)B * 4);
    float* g          = (float*)carve((size_t)N * DIN * 4);
    float* act        = (float*)carve((size_t)N * DH * 4);
    (void)ws_size;

    int nb_e   = (E + 255) / 256;
    int nb_agg = (N + 3) / 4;

    // CSR build
    init_k<<<(Npad + 255) / 256, 256, 0, stream>>>(deg, cnt, Npad, N);
    hist_deg<<<nb_e, 256, 0, stream>>>(e_dst, deg, E);
    scan_phase1<<<B, 256, 0, stream>>>(deg, block_sums);
    scan_phase2<<<1, 256, 0, stream>>>(block_sums, block_off, row_ptr, B, N);
    scan_phase3<<<B, 256, 0, stream>>>(deg, block_off, row_ptr, dis, N);
    fill_csr<<<nb_e, 256, 0, stream>>>(e_src, e_dst, row_ptr, cnt, csr_src, E);

    // Layer 1: x[N,128] @ W1 -> g; aggregate+relu -> act
    gemm_scale<128, 64><<<(N + 63) / 64, 256, 0, stream>>>(x, W1, dis, g, N);
    aggregate<64, true><<<nb_agg, 256, 0, stream>>>(g, row_ptr, csr_src, dis, b1, act, N);

    // Layer 2: act @ W2 -> g; aggregate+relu -> z (d_out)
    gemm_scale<64, 64><<<(N + 63) / 64, 256, 0, stream>>>(act, W2, dis, g, N);
    aggregate<64, true><<<nb_agg, 256, 0, stream>>>(g, row_ptr, csr_src, dis, b2, z, N);

    // Layer 3: z @ W3 -> g; aggregate+relu -> act
    gemm_scale<64, 64><<<(N + 63) / 64, 256, 0, stream>>>(z, W3, dis, g, N);
    aggregate<64, true><<<nb_agg, 256, 0, stream>>>(g, row_ptr, csr_src, dis, b3, act, N);

    // Layer 4: act @ W4 -> g; aggregate (no relu) -> x_hat (d_out)
    gemm_scale<64, 128><<<(N + 31) / 32, 256, 0, stream>>>(act, W4, dis, g, N);
    aggregate<128, false><<<nb_agg, 256, 0, stream>>>(g, row_ptr, csr_src, dis, b4, x_hat, N);
}

// Round 3
// 381.928 us; speedup vs baseline: 1.5558x; 1.3002x over previous
//
#include <hip/hip_runtime.h>
#include <hip/hip_bf16.h>

// DOMINANT GCN autoencoder on MI355X.
// R3 change: aggregate edge-loop unrolled x4 with independent accumulators
// (4x memory-level parallelism; was latency-bound at 2.5 TB/s effective).
// Everything else unchanged from R2 (497us total).

// ---------------- CSR build ----------------

__global__ __launch_bounds__(256) void init_k(int* __restrict__ deg,
                                              int* __restrict__ cnt,
                                              int Npad, int N) {
    int i = blockIdx.x * 256 + threadIdx.x;
    if (i < Npad) deg[i] = 0;
    if (i < N)    cnt[i] = 0;
}

__global__ __launch_bounds__(256) void hist_deg(const int* __restrict__ dst,
                                                int* __restrict__ deg, int E) {
    int e = blockIdx.x * 256 + threadIdx.x;
    if (e < E) atomicAdd(&deg[dst[e]], 1);
}

// Phase 1: per-block (2048 nodes) sum of deg -> block_sums[b]
__global__ __launch_bounds__(256) void scan_phase1(const int* __restrict__ deg,
                                                   int* __restrict__ block_sums) {
    int b = blockIdx.x, t = threadIdx.x;
    const int4* p = reinterpret_cast<const int4*>(deg + (size_t)b * 2048);
    int4 a = p[t * 2], c = p[t * 2 + 1];
    int s = a.x + a.y + a.z + a.w + c.x + c.y + c.z + c.w;
#pragma unroll
    for (int off = 32; off; off >>= 1) s += __shfl_down(s, off);
    __shared__ int wsum[4];
    if ((t & 63) == 0) wsum[t >> 6] = s;
    __syncthreads();
    if (t == 0) block_sums[b] = wsum[0] + wsum[1] + wsum[2] + wsum[3];
}

// Phase 2: single block scans <=256 block sums -> exclusive block_off;
// writes row_ptr[N] = total.
__global__ __launch_bounds__(256) void scan_phase2(const int* __restrict__ block_sums,
                                                   int* __restrict__ block_off,
                                                   int* __restrict__ row_ptr,
                                                   int B, int N) {
    __shared__ int s[256];
    int t = threadIdx.x;
    int v = (t < B) ? block_sums[t] : 0;
    s[t] = v;
    __syncthreads();
#pragma unroll
    for (int off = 1; off < 256; off <<= 1) {
        int u = (t >= off) ? s[t - off] : 0;
        __syncthreads();
        s[t] += u;
        __syncthreads();
    }
    if (t < B) block_off[t] = s[t] - v;
    if (t == 255) row_ptr[N] = s[255];
}

// Phase 3: per-block exclusive scan of 2048 deg + block offset -> row_ptr;
// also dis = rsqrt(deg+1).
__global__ __launch_bounds__(256) void scan_phase3(const int* __restrict__ deg,
                                                   const int* __restrict__ block_off,
                                                   int* __restrict__ row_ptr,
                                                   float* __restrict__ dis, int N) {
    int b = blockIdx.x, t = threadIdx.x;
    int base = b * 2048 + t * 8;
    const int4* p = reinterpret_cast<const int4*>(deg + base);
    int4 a = p[0], c = p[1];
    int d[8] = {a.x, a.y, a.z, a.w, c.x, c.y, c.z, c.w};
    int pre[8], s = 0;
#pragma unroll
    for (int j = 0; j < 8; ++j) { pre[j] = s; s += d[j]; }
    __shared__ int ls[256];
    ls[t] = s;
    __syncthreads();
#pragma unroll
    for (int off = 1; off < 256; off <<= 1) {
        int u = (t >= off) ? ls[t - off] : 0;
        __syncthreads();
        ls[t] += u;
        __syncthreads();
    }
    int excl = ls[t] - s + block_off[b];
#pragma unroll
    for (int j = 0; j < 8; ++j) {
        int i = base + j;
        if (i < N) {
            row_ptr[i] = excl + pre[j];
            dis[i] = rsqrtf((float)(d[j] + 1));
        }
    }
}

__global__ __launch_bounds__(256) void fill_csr(const int* __restrict__ src,
                                                const int* __restrict__ dst,
                                                const int* __restrict__ row_ptr,
                                                int* __restrict__ cnt,
                                                int* __restrict__ csr_src, int E) {
    int e = blockIdx.x * 256 + threadIdx.x;
    if (e < E) {
        int d = dst[e];
        int pos = row_ptr[d] + atomicAdd(&cnt[d], 1);
        csr_src[pos] = src[e];
    }
}

// ---------------- GEMM with row-scale epilogue ----------------
template <int K, int DOUT>
__global__ __launch_bounds__(256) void gemm_scale(const float* __restrict__ A,
                                                  const float* __restrict__ W,
                                                  const float* __restrict__ dis,
                                                  float* __restrict__ G, int N) {
    constexpr int CG   = DOUT / 4;
    constexpr int RG   = 256 / CG;
    constexpr int ROWS = RG * 4;
    constexpr int LDA  = K + 1;

    __shared__ __align__(16) float a_lds[ROWS * LDA];
    __shared__ __align__(16) float w_lds[K * DOUT];

    int t    = threadIdx.x;
    int row0 = blockIdx.x * ROWS;

    constexpr int WF4 = K * DOUT / 4;
    for (int q = t; q < WF4; q += 256)
        reinterpret_cast<float4*>(w_lds)[q] =
            reinterpret_cast<const float4*>(W)[q];

    constexpr int AF4 = ROWS * K / 4;
    for (int q = t; q < AF4; q += 256) {
        int r  = q / (K / 4);
        int kc = q % (K / 4);
        float4 v = make_float4(0.f, 0.f, 0.f, 0.f);
        int gr = row0 + r;
        if (gr < N)
            v = reinterpret_cast<const float4*>(A + (size_t)gr * K)[kc];
        float* p = &a_lds[r * LDA + kc * 4];
        p[0] = v.x; p[1] = v.y; p[2] = v.z; p[3] = v.w;
    }
    __syncthreads();

    int c0 = (t % CG) * 4;
    int r0 = (t / CG) * 4;

    float4 acc[4] = {};
#pragma unroll 4
    for (int k = 0; k < K; ++k) {
        float4 w4 = *reinterpret_cast<const float4*>(&w_lds[k * DOUT + c0]);
#pragma unroll
        for (int j = 0; j < 4; ++j) {
            float a = a_lds[(r0 + j) * LDA + k];
            acc[j].x += a * w4.x;
            acc[j].y += a * w4.y;
            acc[j].z += a * w4.z;
            acc[j].w += a * w4.w;
        }
    }

#pragma unroll
    for (int j = 0; j < 4; ++j) {
        int gr = row0 + r0 + j;
        if (gr < N) {
            float s = dis[gr];
            float4 o = acc[j];
            o.x *= s; o.y *= s; o.z *= s; o.w *= s;
            reinterpret_cast<float4*>(G + (size_t)gr * DOUT)[c0 / 4] = o;
        }
    }
}

// ---------------- Aggregation (gather, no atomics, 4-edge MLP) ----------------
template <int D, bool RELU>
__global__ __launch_bounds__(256) void aggregate(const float* __restrict__ G,
                                                 const int* __restrict__ row_ptr,
                                                 const int* __restrict__ csr_src,
                                                 const float* __restrict__ dis,
                                                 const float* __restrict__ bias,
                                                 float* __restrict__ Out, int N) {
    constexpr int F = D / 64;
    int wave = threadIdx.x >> 6;
    int lane = threadIdx.x & 63;
    int n = blockIdx.x * 4 + wave;
    if (n >= N) return;

    float acc0[F], acc1[F] = {}, acc2[F] = {}, acc3[F] = {};
#pragma unroll
    for (int j = 0; j < F; ++j)
        acc0[j] = G[(size_t)n * D + j * 64 + lane];   // self-loop term

    int beg = row_ptr[n];
    int end = row_ptr[n + 1];
    int i = beg;
    for (; i + 4 <= end; i += 4) {
        int s0 = csr_src[i];
        int s1 = csr_src[i + 1];
        int s2 = csr_src[i + 2];
        int s3 = csr_src[i + 3];
        const float* g0 = G + (size_t)s0 * D + lane;
        const float* g1 = G + (size_t)s1 * D + lane;
        const float* g2 = G + (size_t)s2 * D + lane;
        const float* g3 = G + (size_t)s3 * D + lane;
#pragma unroll
        for (int j = 0; j < F; ++j) {
            float v0 = g0[j * 64];
            float v1 = g1[j * 64];
            float v2 = g2[j * 64];
            float v3 = g3[j * 64];
            acc0[j] += v0;
            acc1[j] += v1;
            acc2[j] += v2;
            acc3[j] += v3;
        }
    }
    for (; i < end; ++i) {
        int s = csr_src[i];
        const float* gs = G + (size_t)s * D + lane;
#pragma unroll
        for (int j = 0; j < F; ++j)
            acc1[j] += gs[j * 64];
    }

    float dn = dis[n];
#pragma unroll
    for (int j = 0; j < F; ++j) {
        float v = dn * ((acc0[j] + acc1[j]) + (acc2[j] + acc3[j])) + bias[j * 64 + lane];
        if (RELU) v = fmaxf(v, 0.f);
        Out[(size_t)n * D + j * 64 + lane] = v;
    }
}

// ---------------- Launch ----------------

extern "C" void kernel_launch(void* const* d_in, const int* in_sizes, int n_in,
                              void* d_out, int out_size, void* d_ws, size_t ws_size,
                              hipStream_t stream) {
    const float* x     = (const float*)d_in[0];
    const int*   edges = (const int*)d_in[1];   // [2, E] row-major
    const float* W1 = (const float*)d_in[2];
    const float* b1 = (const float*)d_in[3];
    const float* W2 = (const float*)d_in[4];
    const float* b2 = (const float*)d_in[5];
    const float* W3 = (const float*)d_in[6];
    const float* b3 = (const float*)d_in[7];
    const float* W4 = (const float*)d_in[8];
    const float* b4 = (const float*)d_in[9];

    const int DIN = 128, DH = 64;
    int N = in_sizes[0] / DIN;
    int E = in_sizes[1] / 2;

    const int* e_src = edges;
    const int* e_dst = edges + E;

    float* out   = (float*)d_out;
    float* x_hat = out;                       // [N,128]
    float* z     = out + (size_t)N * DIN;     // [N,64]

    int B    = (N + 2047) / 2048;
    int Npad = B * 2048;

    char*  ws  = (char*)d_ws;
    size_t off = 0;
    auto carve = [&](size_t bytes) {
        void* p = ws + off;
        off = (off + bytes + 255) & ~(size_t)255;
        return p;
    };
    float* dis        = (float*)carve((size_t)N * 4);
    int*   deg        = (int*)  carve((size_t)Npad * 4);
    int*   cnt        = (int*)  carve((size_t)N * 4);
    int*   row_ptr    = (int*)  carve((size_t)(N + 1) * 4);
    int*   csr_src    = (int*)  carve((size_t)E * 4);
    int*   block_sums = (int*)  carve((size_t)B * 4);
    int*   block_off  = (int*)  carve((size_t)B * 4);
    float* g          = (float*)carve((size_t)N * DIN * 4);
    float* act        = (float*)carve((size_t)N * DH * 4);
    (void)ws_size;

    int nb_e   = (E + 255) / 256;
    int nb_agg = (N + 3) / 4;

    // CSR build
    init_k<<<(Npad + 255) / 256, 256, 0, stream>>>(deg, cnt, Npad, N);
    hist_deg<<<nb_e, 256, 0, stream>>>(e_dst, deg, E);
    scan_phase1<<<B, 256, 0, stream>>>(deg, block_sums);
    scan_phase2<<<1, 256, 0, stream>>>(block_sums, block_off, row_ptr, B, N);
    scan_phase3<<<B, 256, 0, stream>>>(deg, block_off, row_ptr, dis, N);
    fill_csr<<<nb_e, 256, 0, stream>>>(e_src, e_dst, row_ptr, cnt, csr_src, E);

    // Layer 1
    gemm_scale<128, 64><<<(N + 63) / 64, 256, 0, stream>>>(x, W1, dis, g, N);
    aggregate<64, true><<<nb_agg, 256, 0, stream>>>(g, row_ptr, csr_src, dis, b1, act, N);

    // Layer 2 -> z (d_out)
    gemm_scale<64, 64><<<(N + 63) / 64, 256, 0, stream>>>(act, W2, dis, g, N);
    aggregate<64, true><<<nb_agg, 256, 0, stream>>>(g, row_ptr, csr_src, dis, b2, z, N);

    // Layer 3
    gemm_scale<64, 64><<<(N + 63) / 64, 256, 0, stream>>>(z, W3, dis, g, N);
    aggregate<64, true><<<nb_agg, 256, 0, stream>>>(g, row_ptr, csr_src, dis, b3, act, N);

    // Layer 4 -> x_hat (d_out)
    gemm_scale<64, 128><<<(N + 31) / 32, 256, 0, stream>>>(act, W4, dis, g, N);
    aggregate<128, false><<<nb_agg, 256, 0, stream>>>(g, row_ptr, csr_src, dis, b4, x_hat, N);
}

// Round 4
// 343.371 us; speedup vs baseline: 1.7305x; 1.1123x over previous
//
#include <hip/hip_runtime.h>
#include <hip/hip_bf16.h>

// DOMINANT GCN autoencoder on MI355X.
// R4 change: gather table g stored in bf16 (fp32 accumulate) -> halves gather
// lines per edge and shrinks table toward L2 capacity. Aggregates were
// line-fill-throughput-bound at 3.7 TB/s effective.
// Everything else unchanged from R3 (382us total).

// ---------------- CSR build ----------------

__global__ __launch_bounds__(256) void init_k(int* __restrict__ deg,
                                              int* __restrict__ cnt,
                                              int Npad, int N) {
    int i = blockIdx.x * 256 + threadIdx.x;
    if (i < Npad) deg[i] = 0;
    if (i < N)    cnt[i] = 0;
}

__global__ __launch_bounds__(256) void hist_deg(const int* __restrict__ dst,
                                                int* __restrict__ deg, int E) {
    int e = blockIdx.x * 256 + threadIdx.x;
    if (e < E) atomicAdd(&deg[dst[e]], 1);
}

__global__ __launch_bounds__(256) void scan_phase1(const int* __restrict__ deg,
                                                   int* __restrict__ block_sums) {
    int b = blockIdx.x, t = threadIdx.x;
    const int4* p = reinterpret_cast<const int4*>(deg + (size_t)b * 2048);
    int4 a = p[t * 2], c = p[t * 2 + 1];
    int s = a.x + a.y + a.z + a.w + c.x + c.y + c.z + c.w;
#pragma unroll
    for (int off = 32; off; off >>= 1) s += __shfl_down(s, off);
    __shared__ int wsum[4];
    if ((t & 63) == 0) wsum[t >> 6] = s;
    __syncthreads();
    if (t == 0) block_sums[b] = wsum[0] + wsum[1] + wsum[2] + wsum[3];
}

__global__ __launch_bounds__(256) void scan_phase2(const int* __restrict__ block_sums,
                                                   int* __restrict__ block_off,
                                                   int* __restrict__ row_ptr,
                                                   int B, int N) {
    __shared__ int s[256];
    int t = threadIdx.x;
    int v = (t < B) ? block_sums[t] : 0;
    s[t] = v;
    __syncthreads();
#pragma unroll
    for (int off = 1; off < 256; off <<= 1) {
        int u = (t >= off) ? s[t - off] : 0;
        __syncthreads();
        s[t] += u;
        __syncthreads();
    }
    if (t < B) block_off[t] = s[t] - v;
    if (t == 255) row_ptr[N] = s[255];
}

__global__ __launch_bounds__(256) void scan_phase3(const int* __restrict__ deg,
                                                   const int* __restrict__ block_off,
                                                   int* __restrict__ row_ptr,
                                                   float* __restrict__ dis, int N) {
    int b = blockIdx.x, t = threadIdx.x;
    int base = b * 2048 + t * 8;
    const int4* p = reinterpret_cast<const int4*>(deg + base);
    int4 a = p[0], c = p[1];
    int d[8] = {a.x, a.y, a.z, a.w, c.x, c.y, c.z, c.w};
    int pre[8], s = 0;
#pragma unroll
    for (int j = 0; j < 8; ++j) { pre[j] = s; s += d[j]; }
    __shared__ int ls[256];
    ls[t] = s;
    __syncthreads();
#pragma unroll
    for (int off = 1; off < 256; off <<= 1) {
        int u = (t >= off) ? ls[t - off] : 0;
        __syncthreads();
        ls[t] += u;
        __syncthreads();
    }
    int excl = ls[t] - s + block_off[b];
#pragma unroll
    for (int j = 0; j < 8; ++j) {
        int i = base + j;
        if (i < N) {
            row_ptr[i] = excl + pre[j];
            dis[i] = rsqrtf((float)(d[j] + 1));
        }
    }
}

__global__ __launch_bounds__(256) void fill_csr(const int* __restrict__ src,
                                                const int* __restrict__ dst,
                                                const int* __restrict__ row_ptr,
                                                int* __restrict__ cnt,
                                                int* __restrict__ csr_src, int E) {
    int e = blockIdx.x * 256 + threadIdx.x;
    if (e < E) {
        int d = dst[e];
        int pos = row_ptr[d] + atomicAdd(&cnt[d], 1);
        csr_src[pos] = src[e];
    }
}

// ---------------- GEMM with row-scale + bf16 epilogue ----------------
// G16[r][c] = bf16( dis[r] * sum_k A[r][k] * W[k][c] )
template <int K, int DOUT>
__global__ __launch_bounds__(256) void gemm_scale(const float* __restrict__ A,
                                                  const float* __restrict__ W,
                                                  const float* __restrict__ dis,
                                                  ushort* __restrict__ G16, int N) {
    constexpr int CG   = DOUT / 4;
    constexpr int RG   = 256 / CG;
    constexpr int ROWS = RG * 4;
    constexpr int LDA  = K + 1;

    __shared__ __align__(16) float a_lds[ROWS * LDA];
    __shared__ __align__(16) float w_lds[K * DOUT];

    int t    = threadIdx.x;
    int row0 = blockIdx.x * ROWS;

    constexpr int WF4 = K * DOUT / 4;
    for (int q = t; q < WF4; q += 256)
        reinterpret_cast<float4*>(w_lds)[q] =
            reinterpret_cast<const float4*>(W)[q];

    constexpr int AF4 = ROWS * K / 4;
    for (int q = t; q < AF4; q += 256) {
        int r  = q / (K / 4);
        int kc = q % (K / 4);
        float4 v = make_float4(0.f, 0.f, 0.f, 0.f);
        int gr = row0 + r;
        if (gr < N)
            v = reinterpret_cast<const float4*>(A + (size_t)gr * K)[kc];
        float* p = &a_lds[r * LDA + kc * 4];
        p[0] = v.x; p[1] = v.y; p[2] = v.z; p[3] = v.w;
    }
    __syncthreads();

    int c0 = (t % CG) * 4;
    int r0 = (t / CG) * 4;

    float4 acc[4] = {};
#pragma unroll 4
    for (int k = 0; k < K; ++k) {
        float4 w4 = *reinterpret_cast<const float4*>(&w_lds[k * DOUT + c0]);
#pragma unroll
        for (int j = 0; j < 4; ++j) {
            float a = a_lds[(r0 + j) * LDA + k];
            acc[j].x += a * w4.x;
            acc[j].y += a * w4.y;
            acc[j].z += a * w4.z;
            acc[j].w += a * w4.w;
        }
    }

    auto r16 = [](float f) -> ushort {
        __hip_bfloat16 h = __float2bfloat16(f);   // round-to-nearest-even
        return *reinterpret_cast<ushort*>(&h);
    };

#pragma unroll
    for (int j = 0; j < 4; ++j) {
        int gr = row0 + r0 + j;
        if (gr < N) {
            float s = dis[gr];
            float4 o = acc[j];
            ushort4 pk;
            pk.x = r16(o.x * s); pk.y = r16(o.y * s);
            pk.z = r16(o.z * s); pk.w = r16(o.w * s);
            *reinterpret_cast<ushort4*>(&G16[(size_t)gr * DOUT + c0]) = pk;
        }
    }
}

// ---------------- Aggregation (bf16 gather, fp32 accumulate) ----------------

__device__ __forceinline__ float bf_up(ushort u) {
    return __builtin_bit_cast(float, (unsigned)u << 16);
}
__device__ __forceinline__ float bf_lo(unsigned u) {
    return __builtin_bit_cast(float, u << 16);
}
__device__ __forceinline__ float bf_hi(unsigned u) {
    return __builtin_bit_cast(float, u & 0xFFFF0000u);
}

// D=64: lane = feature; ushort gathers (128 B/row = 2 lines).
template <bool RELU>
__global__ __launch_bounds__(256) void aggregate_bf64(const ushort* __restrict__ G,
                                                      const int* __restrict__ row_ptr,
                                                      const int* __restrict__ csr_src,
                                                      const float* __restrict__ dis,
                                                      const float* __restrict__ bias,
                                                      float* __restrict__ Out, int N) {
    int wave = threadIdx.x >> 6;
    int lane = threadIdx.x & 63;
    int n = blockIdx.x * 4 + wave;
    if (n >= N) return;

    float a0 = bf_up(G[(size_t)n * 64 + lane]);   // self-loop term
    float a1 = 0.f, a2 = 0.f, a3 = 0.f;

    int beg = row_ptr[n];
    int end = row_ptr[n + 1];
    int i = beg;
    for (; i + 8 <= end; i += 8) {
        int s0 = csr_src[i],     s1 = csr_src[i + 1];
        int s2 = csr_src[i + 2], s3 = csr_src[i + 3];
        int s4 = csr_src[i + 4], s5 = csr_src[i + 5];
        int s6 = csr_src[i + 6], s7 = csr_src[i + 7];
        ushort u0 = G[(size_t)s0 * 64 + lane];
        ushort u1 = G[(size_t)s1 * 64 + lane];
        ushort u2 = G[(size_t)s2 * 64 + lane];
        ushort u3 = G[(size_t)s3 * 64 + lane];
        ushort u4 = G[(size_t)s4 * 64 + lane];
        ushort u5 = G[(size_t)s5 * 64 + lane];
        ushort u6 = G[(size_t)s6 * 64 + lane];
        ushort u7 = G[(size_t)s7 * 64 + lane];
        a0 += bf_up(u0) + bf_up(u4);
        a1 += bf_up(u1) + bf_up(u5);
        a2 += bf_up(u2) + bf_up(u6);
        a3 += bf_up(u3) + bf_up(u7);
    }
    for (; i + 4 <= end; i += 4) {
        int s0 = csr_src[i],     s1 = csr_src[i + 1];
        int s2 = csr_src[i + 2], s3 = csr_src[i + 3];
        ushort u0 = G[(size_t)s0 * 64 + lane];
        ushort u1 = G[(size_t)s1 * 64 + lane];
        ushort u2 = G[(size_t)s2 * 64 + lane];
        ushort u3 = G[(size_t)s3 * 64 + lane];
        a0 += bf_up(u0);
        a1 += bf_up(u1);
        a2 += bf_up(u2);
        a3 += bf_up(u3);
    }
    for (; i < end; ++i)
        a1 += bf_up(G[(size_t)csr_src[i] * 64 + lane]);

    float v = dis[n] * ((a0 + a1) + (a2 + a3)) + bias[lane];
    if (RELU) v = fmaxf(v, 0.f);
    Out[(size_t)n * 64 + lane] = v;
}

// D=128: lane owns feature pair (2*lane, 2*lane+1); uint gathers
// (256 B/row = 4 lines, one load-inst per edge).
template <bool RELU>
__global__ __launch_bounds__(256) void aggregate_bf128(const unsigned* __restrict__ G,
                                                       const int* __restrict__ row_ptr,
                                                       const int* __restrict__ csr_src,
                                                       const float* __restrict__ dis,
                                                       const float* __restrict__ bias,
                                                       float* __restrict__ Out, int N) {
    int wave = threadIdx.x >> 6;
    int lane = threadIdx.x & 63;
    int n = blockIdx.x * 4 + wave;
    if (n >= N) return;

    unsigned su = G[(size_t)n * 64 + lane];   // self-loop pair
    float l0 = bf_lo(su), h0 = bf_hi(su);
    float l1 = 0.f, h1 = 0.f, l2 = 0.f, h2 = 0.f, l3 = 0.f, h3 = 0.f;

    int beg = row_ptr[n];
    int end = row_ptr[n + 1];
    int i = beg;
    for (; i + 4 <= end; i += 4) {
        int s0 = csr_src[i],     s1 = csr_src[i + 1];
        int s2 = csr_src[i + 2], s3 = csr_src[i + 3];
        unsigned u0 = G[(size_t)s0 * 64 + lane];
        unsigned u1 = G[(size_t)s1 * 64 + lane];
        unsigned u2 = G[(size_t)s2 * 64 + lane];
        unsigned u3 = G[(size_t)s3 * 64 + lane];
        l0 += bf_lo(u0); h0 += bf_hi(u0);
        l1 += bf_lo(u1); h1 += bf_hi(u1);
        l2 += bf_lo(u2); h2 += bf_hi(u2);
        l3 += bf_lo(u3); h3 += bf_hi(u3);
    }
    for (; i < end; ++i) {
        unsigned u = G[(size_t)csr_src[i] * 64 + lane];
        l1 += bf_lo(u); h1 += bf_hi(u);
    }

    float dn = dis[n];
    float2 b2 = reinterpret_cast<const float2*>(bias)[lane];
    float vlo = dn * ((l0 + l1) + (l2 + l3)) + b2.x;
    float vhi = dn * ((h0 + h1) + (h2 + h3)) + b2.y;
    if (RELU) { vlo = fmaxf(vlo, 0.f); vhi = fmaxf(vhi, 0.f); }
    reinterpret_cast<float2*>(Out + (size_t)n * 128)[lane] = make_float2(vlo, vhi);
}

// ---------------- Launch ----------------

extern "C" void kernel_launch(void* const* d_in, const int* in_sizes, int n_in,
                              void* d_out, int out_size, void* d_ws, size_t ws_size,
                              hipStream_t stream) {
    const float* x     = (const float*)d_in[0];
    const int*   edges = (const int*)d_in[1];   // [2, E] row-major
    const float* W1 = (const float*)d_in[2];
    const float* b1 = (const float*)d_in[3];
    const float* W2 = (const float*)d_in[4];
    const float* b2 = (const float*)d_in[5];
    const float* W3 = (const float*)d_in[6];
    const float* b3 = (const float*)d_in[7];
    const float* W4 = (const float*)d_in[8];
    const float* b4 = (const float*)d_in[9];

    const int DIN = 128, DH = 64;
    int N = in_sizes[0] / DIN;
    int E = in_sizes[1] / 2;

    const int* e_src = edges;
    const int* e_dst = edges + E;

    float* out   = (float*)d_out;
    float* x_hat = out;                       // [N,128]
    float* z     = out + (size_t)N * DIN;     // [N,64]

    int B    = (N + 2047) / 2048;
    int Npad = B * 2048;

    char*  ws  = (char*)d_ws;
    size_t off = 0;
    auto carve = [&](size_t bytes) {
        void* p = ws + off;
        off = (off + bytes + 255) & ~(size_t)255;
        return p;
    };
    float*  dis        = (float*) carve((size_t)N * 4);
    int*    deg        = (int*)   carve((size_t)Npad * 4);
    int*    cnt        = (int*)   carve((size_t)N * 4);
    int*    row_ptr    = (int*)   carve((size_t)(N + 1) * 4);
    int*    csr_src    = (int*)   carve((size_t)E * 4);
    int*    block_sums = (int*)   carve((size_t)B * 4);
    int*    block_off  = (int*)   carve((size_t)B * 4);
    ushort* g16        = (ushort*)carve((size_t)N * DIN * 2);  // bf16, widest layer
    float*  act        = (float*) carve((size_t)N * DH * 4);
    (void)ws_size;

    int nb_e   = (E + 255) / 256;
    int nb_agg = (N + 3) / 4;

    // CSR build
    init_k<<<(Npad + 255) / 256, 256, 0, stream>>>(deg, cnt, Npad, N);
    hist_deg<<<nb_e, 256, 0, stream>>>(e_dst, deg, E);
    scan_phase1<<<B, 256, 0, stream>>>(deg, block_sums);
    scan_phase2<<<1, 256, 0, stream>>>(block_sums, block_off, row_ptr, B, N);
    scan_phase3<<<B, 256, 0, stream>>>(deg, block_off, row_ptr, dis, N);
    fill_csr<<<nb_e, 256, 0, stream>>>(e_src, e_dst, row_ptr, cnt, csr_src, E);

    // Layer 1
    gemm_scale<128, 64><<<(N + 63) / 64, 256, 0, stream>>>(x, W1, dis, g16, N);
    aggregate_bf64<true><<<nb_agg, 256, 0, stream>>>(g16, row_ptr, csr_src, dis, b1, act, N);

    // Layer 2 -> z (d_out)
    gemm_scale<64, 64><<<(N + 63) / 64, 256, 0, stream>>>(act, W2, dis, g16, N);
    aggregate_bf64<true><<<nb_agg, 256, 0, stream>>>(g16, row_ptr, csr_src, dis, b2, z, N);

    // Layer 3
    gemm_scale<64, 64><<<(N + 63) / 64, 256, 0, stream>>>(z, W3, dis, g16, N);
    aggregate_bf64<true><<<nb_agg, 256, 0, stream>>>(g16, row_ptr, csr_src, dis, b3, act, N);

    // Layer 4 -> x_hat (d_out)
    gemm_scale<64, 128><<<(N + 31) / 32, 256, 0, stream>>>(act, W4, dis, g16, N);
    aggregate_bf128<false><<<nb_agg, 256, 0, stream>>>((const unsigned*)g16, row_ptr,
                                                       csr_src, dis, b4, x_hat, N);
}

// Round 5
// 335.294 us; speedup vs baseline: 1.7721x; 1.0241x over previous
//
#include <hip/hip_runtime.h>
#include <hip/hip_bf16.h>

// DOMINANT GCN autoencoder on MI355X.
// R5 change: layer-4 reassociated as (A_hat . a3) W4 + b4 -> aggregation runs
// in 64-dim bf16 (82 MB gather lines) instead of 128-dim (164 MB); layer-3
// aggregate emits bf16(dis*relu) directly; final GEMM fuses bias, fp32 out.
// Everything else unchanged from R4 (343us total).

// ---------------- CSR build ----------------

__global__ __launch_bounds__(256) void init_k(int* __restrict__ deg,
                                              int* __restrict__ cnt,
                                              int Npad, int N) {
    int i = blockIdx.x * 256 + threadIdx.x;
    if (i < Npad) deg[i] = 0;
    if (i < N)    cnt[i] = 0;
}

__global__ __launch_bounds__(256) void hist_deg(const int* __restrict__ dst,
                                                int* __restrict__ deg, int E) {
    int e = blockIdx.x * 256 + threadIdx.x;
    if (e < E) atomicAdd(&deg[dst[e]], 1);
}

__global__ __launch_bounds__(256) void scan_phase1(const int* __restrict__ deg,
                                                   int* __restrict__ block_sums) {
    int b = blockIdx.x, t = threadIdx.x;
    const int4* p = reinterpret_cast<const int4*>(deg + (size_t)b * 2048);
    int4 a = p[t * 2], c = p[t * 2 + 1];
    int s = a.x + a.y + a.z + a.w + c.x + c.y + c.z + c.w;
#pragma unroll
    for (int off = 32; off; off >>= 1) s += __shfl_down(s, off);
    __shared__ int wsum[4];
    if ((t & 63) == 0) wsum[t >> 6] = s;
    __syncthreads();
    if (t == 0) block_sums[b] = wsum[0] + wsum[1] + wsum[2] + wsum[3];
}

__global__ __launch_bounds__(256) void scan_phase2(const int* __restrict__ block_sums,
                                                   int* __restrict__ block_off,
                                                   int* __restrict__ row_ptr,
                                                   int B, int N) {
    __shared__ int s[256];
    int t = threadIdx.x;
    int v = (t < B) ? block_sums[t] : 0;
    s[t] = v;
    __syncthreads();
#pragma unroll
    for (int off = 1; off < 256; off <<= 1) {
        int u = (t >= off) ? s[t - off] : 0;
        __syncthreads();
        s[t] += u;
        __syncthreads();
    }
    if (t < B) block_off[t] = s[t] - v;
    if (t == 255) row_ptr[N] = s[255];
}

__global__ __launch_bounds__(256) void scan_phase3(const int* __restrict__ deg,
                                                   const int* __restrict__ block_off,
                                                   int* __restrict__ row_ptr,
                                                   float* __restrict__ dis, int N) {
    int b = blockIdx.x, t = threadIdx.x;
    int base = b * 2048 + t * 8;
    const int4* p = reinterpret_cast<const int4*>(deg + base);
    int4 a = p[0], c = p[1];
    int d[8] = {a.x, a.y, a.z, a.w, c.x, c.y, c.z, c.w};
    int pre[8], s = 0;
#pragma unroll
    for (int j = 0; j < 8; ++j) { pre[j] = s; s += d[j]; }
    __shared__ int ls[256];
    ls[t] = s;
    __syncthreads();
#pragma unroll
    for (int off = 1; off < 256; off <<= 1) {
        int u = (t >= off) ? ls[t - off] : 0;
        __syncthreads();
        ls[t] += u;
        __syncthreads();
    }
    int excl = ls[t] - s + block_off[b];
#pragma unroll
    for (int j = 0; j < 8; ++j) {
        int i = base + j;
        if (i < N) {
            row_ptr[i] = excl + pre[j];
            dis[i] = rsqrtf((float)(d[j] + 1));
        }
    }
}

__global__ __launch_bounds__(256) void fill_csr(const int* __restrict__ src,
                                                const int* __restrict__ dst,
                                                const int* __restrict__ row_ptr,
                                                int* __restrict__ cnt,
                                                int* __restrict__ csr_src, int E) {
    int e = blockIdx.x * 256 + threadIdx.x;
    if (e < E) {
        int d = dst[e];
        int pos = row_ptr[d] + atomicAdd(&cnt[d], 1);
        csr_src[pos] = src[e];
    }
}

// ---------------- helpers ----------------

__device__ __forceinline__ ushort r16(float f) {
    __hip_bfloat16 h = __float2bfloat16(f);   // round-to-nearest-even
    return *reinterpret_cast<ushort*>(&h);
}
__device__ __forceinline__ float bf_up(ushort u) {
    return __builtin_bit_cast(float, (unsigned)u << 16);
}

// ---------------- GEMM, row-scale + bf16 epilogue ----------------
// G16[r][c] = bf16( dis[r] * sum_k A[r][k] * W[k][c] )
template <int K, int DOUT>
__global__ __launch_bounds__(256) void gemm_scale(const float* __restrict__ A,
                                                  const float* __restrict__ W,
                                                  const float* __restrict__ dis,
                                                  ushort* __restrict__ G16, int N) {
    constexpr int CG   = DOUT / 4;
    constexpr int RG   = 256 / CG;
    constexpr int ROWS = RG * 4;
    constexpr int LDA  = K + 1;

    __shared__ __align__(16) float a_lds[ROWS * LDA];
    __shared__ __align__(16) float w_lds[K * DOUT];

    int t    = threadIdx.x;
    int row0 = blockIdx.x * ROWS;

    constexpr int WF4 = K * DOUT / 4;
    for (int q = t; q < WF4; q += 256)
        reinterpret_cast<float4*>(w_lds)[q] =
            reinterpret_cast<const float4*>(W)[q];

    constexpr int AF4 = ROWS * K / 4;
    for (int q = t; q < AF4; q += 256) {
        int r  = q / (K / 4);
        int kc = q % (K / 4);
        float4 v = make_float4(0.f, 0.f, 0.f, 0.f);
        int gr = row0 + r;
        if (gr < N)
            v = reinterpret_cast<const float4*>(A + (size_t)gr * K)[kc];
        float* p = &a_lds[r * LDA + kc * 4];
        p[0] = v.x; p[1] = v.y; p[2] = v.z; p[3] = v.w;
    }
    __syncthreads();

    int c0 = (t % CG) * 4;
    int r0 = (t / CG) * 4;

    float4 acc[4] = {};
#pragma unroll 4
    for (int k = 0; k < K; ++k) {
        float4 w4 = *reinterpret_cast<const float4*>(&w_lds[k * DOUT + c0]);
#pragma unroll
        for (int j = 0; j < 4; ++j) {
            float a = a_lds[(r0 + j) * LDA + k];
            acc[j].x += a * w4.x;
            acc[j].y += a * w4.y;
            acc[j].z += a * w4.z;
            acc[j].w += a * w4.w;
        }
    }

#pragma unroll
    for (int j = 0; j < 4; ++j) {
        int gr = row0 + r0 + j;
        if (gr < N) {
            float s = dis[gr];
            float4 o = acc[j];
            ushort4 pk;
            pk.x = r16(o.x * s); pk.y = r16(o.y * s);
            pk.z = r16(o.z * s); pk.w = r16(o.w * s);
            *reinterpret_cast<ushort4*>(&G16[(size_t)gr * DOUT + c0]) = pk;
        }
    }
}

// ---------------- GEMM, bias epilogue, fp32 out (final layer) ----------------
template <int K, int DOUT>
__global__ __launch_bounds__(256) void gemm_bias(const float* __restrict__ A,
                                                 const float* __restrict__ W,
                                                 const float* __restrict__ bias,
                                                 float* __restrict__ Out, int N) {
    constexpr int CG   = DOUT / 4;
    constexpr int RG   = 256 / CG;
    constexpr int ROWS = RG * 4;
    constexpr int LDA  = K + 1;

    __shared__ __align__(16) float a_lds[ROWS * LDA];
    __shared__ __align__(16) float w_lds[K * DOUT];

    int t    = threadIdx.x;
    int row0 = blockIdx.x * ROWS;

    constexpr int WF4 = K * DOUT / 4;
    for (int q = t; q < WF4; q += 256)
        reinterpret_cast<float4*>(w_lds)[q] =
            reinterpret_cast<const float4*>(W)[q];

    constexpr int AF4 = ROWS * K / 4;
    for (int q = t; q < AF4; q += 256) {
        int r  = q / (K / 4);
        int kc = q % (K / 4);
        float4 v = make_float4(0.f, 0.f, 0.f, 0.f);
        int gr = row0 + r;
        if (gr < N)
            v = reinterpret_cast<const float4*>(A + (size_t)gr * K)[kc];
        float* p = &a_lds[r * LDA + kc * 4];
        p[0] = v.x; p[1] = v.y; p[2] = v.z; p[3] = v.w;
    }
    __syncthreads();

    int c0 = (t % CG) * 4;
    int r0 = (t / CG) * 4;

    float4 acc[4] = {};
#pragma unroll 4
    for (int k = 0; k < K; ++k) {
        float4 w4 = *reinterpret_cast<const float4*>(&w_lds[k * DOUT + c0]);
#pragma unroll
        for (int j = 0; j < 4; ++j) {
            float a = a_lds[(r0 + j) * LDA + k];
            acc[j].x += a * w4.x;
            acc[j].y += a * w4.y;
            acc[j].z += a * w4.z;
            acc[j].w += a * w4.w;
        }
    }

    float4 b4v = *reinterpret_cast<const float4*>(&bias[c0]);
#pragma unroll
    for (int j = 0; j < 4; ++j) {
        int gr = row0 + r0 + j;
        if (gr < N) {
            float4 o = acc[j];
            o.x += b4v.x; o.y += b4v.y; o.z += b4v.z; o.w += b4v.w;
            reinterpret_cast<float4*>(Out + (size_t)gr * DOUT)[c0 / 4] = o;
        }
    }
}

// ---------------- Aggregation (bf16 gather, fp32 accumulate, D=64) ----------
// v = dis[n] * (G[n] + sum_{src} G[src]) [+ bias] [relu]
// OUT16: store bf16(dis[n]*v) (table for the NEXT aggregation);
// else:  store fp32 v.
template <bool RELU, bool OUT16, bool BIAS>
__global__ __launch_bounds__(256) void aggregate_bf64(const ushort* __restrict__ G,
                                                      const int* __restrict__ row_ptr,
                                                      const int* __restrict__ csr_src,
                                                      const float* __restrict__ dis,
                                                      const float* __restrict__ bias,
                                                      void* __restrict__ OutV, int N) {
    int wave = threadIdx.x >> 6;
    int lane = threadIdx.x & 63;
    int n = blockIdx.x * 4 + wave;
    if (n >= N) return;

    float a0 = bf_up(G[(size_t)n * 64 + lane]);   // self-loop term
    float a1 = 0.f, a2 = 0.f, a3 = 0.f;

    int beg = row_ptr[n];
    int end = row_ptr[n + 1];
    int i = beg;
    for (; i + 8 <= end; i += 8) {
        int s0 = csr_src[i],     s1 = csr_src[i + 1];
        int s2 = csr_src[i + 2], s3 = csr_src[i + 3];
        int s4 = csr_src[i + 4], s5 = csr_src[i + 5];
        int s6 = csr_src[i + 6], s7 = csr_src[i + 7];
        ushort u0 = G[(size_t)s0 * 64 + lane];
        ushort u1 = G[(size_t)s1 * 64 + lane];
        ushort u2 = G[(size_t)s2 * 64 + lane];
        ushort u3 = G[(size_t)s3 * 64 + lane];
        ushort u4 = G[(size_t)s4 * 64 + lane];
        ushort u5 = G[(size_t)s5 * 64 + lane];
        ushort u6 = G[(size_t)s6 * 64 + lane];
        ushort u7 = G[(size_t)s7 * 64 + lane];
        a0 += bf_up(u0) + bf_up(u4);
        a1 += bf_up(u1) + bf_up(u5);
        a2 += bf_up(u2) + bf_up(u6);
        a3 += bf_up(u3) + bf_up(u7);
    }
    for (; i + 4 <= end; i += 4) {
        int s0 = csr_src[i],     s1 = csr_src[i + 1];
        int s2 = csr_src[i + 2], s3 = csr_src[i + 3];
        ushort u0 = G[(size_t)s0 * 64 + lane];
        ushort u1 = G[(size_t)s1 * 64 + lane];
        ushort u2 = G[(size_t)s2 * 64 + lane];
        ushort u3 = G[(size_t)s3 * 64 + lane];
        a0 += bf_up(u0);
        a1 += bf_up(u1);
        a2 += bf_up(u2);
        a3 += bf_up(u3);
    }
    for (; i < end; ++i)
        a1 += bf_up(G[(size_t)csr_src[i] * 64 + lane]);

    float dn = dis[n];
    float v = dn * ((a0 + a1) + (a2 + a3));
    if (BIAS) v += bias[lane];
    if (RELU) v = fmaxf(v, 0.f);
    if (OUT16)
        ((ushort*)OutV)[(size_t)n * 64 + lane] = r16(dn * v);
    else
        ((float*)OutV)[(size_t)n * 64 + lane] = v;
}

// ---------------- Launch ----------------

extern "C" void kernel_launch(void* const* d_in, const int* in_sizes, int n_in,
                              void* d_out, int out_size, void* d_ws, size_t ws_size,
                              hipStream_t stream) {
    const float* x     = (const float*)d_in[0];
    const int*   edges = (const int*)d_in[1];   // [2, E] row-major
    const float* W1 = (const float*)d_in[2];
    const float* b1 = (const float*)d_in[3];
    const float* W2 = (const float*)d_in[4];
    const float* b2 = (const float*)d_in[5];
    const float* W3 = (const float*)d_in[6];
    const float* b3 = (const float*)d_in[7];
    const float* W4 = (const float*)d_in[8];
    const float* b4 = (const float*)d_in[9];

    const int DIN = 128, DH = 64;
    int N = in_sizes[0] / DIN;
    int E = in_sizes[1] / 2;

    const int* e_src = edges;
    const int* e_dst = edges + E;

    float* out   = (float*)d_out;
    float* x_hat = out;                       // [N,128]
    float* z     = out + (size_t)N * DIN;     // [N,64]

    int B    = (N + 2047) / 2048;
    int Npad = B * 2048;

    char*  ws  = (char*)d_ws;
    size_t off = 0;
    auto carve = [&](size_t bytes) {
        void* p = ws + off;
        off = (off + bytes + 255) & ~(size_t)255;
        return p;
    };
    float*  dis        = (float*) carve((size_t)N * 4);
    int*    deg        = (int*)   carve((size_t)Npad * 4);
    int*    cnt        = (int*)   carve((size_t)N * 4);
    int*    row_ptr    = (int*)   carve((size_t)(N + 1) * 4);
    int*    csr_src    = (int*)   carve((size_t)E * 4);
    int*    block_sums = (int*)   carve((size_t)B * 4);
    int*    block_off  = (int*)   carve((size_t)B * 4);
    ushort* g16        = (ushort*)carve((size_t)N * DH * 2);   // gather table
    ushort* s3         = (ushort*)carve((size_t)N * DH * 2);   // layer-3 scaled out
    float*  t          = (float*) carve((size_t)N * DH * 4);   // layer-4 agg result
    float*  act        = (float*) carve((size_t)N * DH * 4);   // h (layer-1 out)
    (void)ws_size;

    int nb_e   = (E + 255) / 256;
    int nb_agg = (N + 3) / 4;

    // CSR build
    init_k<<<(Npad + 255) / 256, 256, 0, stream>>>(deg, cnt, Npad, N);
    hist_deg<<<nb_e, 256, 0, stream>>>(e_dst, deg, E);
    scan_phase1<<<B, 256, 0, stream>>>(deg, block_sums);
    scan_phase2<<<1, 256, 0, stream>>>(block_sums, block_off, row_ptr, B, N);
    scan_phase3<<<B, 256, 0, stream>>>(deg, block_off, row_ptr, dis, N);
    fill_csr<<<nb_e, 256, 0, stream>>>(e_src, e_dst, row_ptr, cnt, csr_src, E);

    // Layer 1: h = relu(dis*(sum g1)+b1), g1 = dis*(x W1)
    gemm_scale<128, 64><<<(N + 63) / 64, 256, 0, stream>>>(x, W1, dis, g16, N);
    aggregate_bf64<true, false, true><<<nb_agg, 256, 0, stream>>>(
        g16, row_ptr, csr_src, dis, b1, act, N);

    // Layer 2: z = relu(...) -> d_out (fp32)
    gemm_scale<64, 64><<<(N + 63) / 64, 256, 0, stream>>>(act, W2, dis, g16, N);
    aggregate_bf64<true, false, true><<<nb_agg, 256, 0, stream>>>(
        g16, row_ptr, csr_src, dis, b2, z, N);

    // Layer 3: s3 = bf16(dis * relu(...))  (table for layer-4 aggregation)
    gemm_scale<64, 64><<<(N + 63) / 64, 256, 0, stream>>>(z, W3, dis, g16, N);
    aggregate_bf64<true, true, true><<<nb_agg, 256, 0, stream>>>(
        g16, row_ptr, csr_src, dis, b3, s3, N);

    // Layer 4 (reassociated): t = dis*(s3[n] + sum s3[src]);  x_hat = t W4 + b4
    aggregate_bf64<false, false, false><<<nb_agg, 256, 0, stream>>>(
        s3, row_ptr, csr_src, dis, nullptr, t, N);
    gemm_bias<64, 128><<<(N + 31) / 32, 256, 0, stream>>>(t, W4, b4, x_hat, N);
}

// Round 7
// 334.125 us; speedup vs baseline: 1.7783x; 1.0035x over previous
//
#include <hip/hip_runtime.h>
#include <hip/hip_bf16.h>

// DOMINANT GCN autoencoder on MI355X.
// R7 = R6 half-wave gather aggregate + FIX: OUT16 epilogue must store
// bf16(dis[n]*v) (the reassociated layer-4 table s3 = dis*relu(a3)); R6
// dropped the dis factor -> absmax 0.476 on x_hat only. One-line fix.
// Base: R5 = 335us total.

// ---------------- CSR build ----------------

__global__ __launch_bounds__(256) void init_k(int* __restrict__ deg,
                                              int* __restrict__ cnt,
                                              int Npad, int N) {
    int i = blockIdx.x * 256 + threadIdx.x;
    if (i < Npad) deg[i] = 0;
    if (i < N)    cnt[i] = 0;
}

__global__ __launch_bounds__(256) void hist_deg(const int* __restrict__ dst,
                                                int* __restrict__ deg, int E) {
    int e = blockIdx.x * 256 + threadIdx.x;
    if (e < E) atomicAdd(&deg[dst[e]], 1);
}

__global__ __launch_bounds__(256) void scan_phase1(const int* __restrict__ deg,
                                                   int* __restrict__ block_sums) {
    int b = blockIdx.x, t = threadIdx.x;
    const int4* p = reinterpret_cast<const int4*>(deg + (size_t)b * 2048);
    int4 a = p[t * 2], c = p[t * 2 + 1];
    int s = a.x + a.y + a.z + a.w + c.x + c.y + c.z + c.w;
#pragma unroll
    for (int off = 32; off; off >>= 1) s += __shfl_down(s, off);
    __shared__ int wsum[4];
    if ((t & 63) == 0) wsum[t >> 6] = s;
    __syncthreads();
    if (t == 0) block_sums[b] = wsum[0] + wsum[1] + wsum[2] + wsum[3];
}

__global__ __launch_bounds__(256) void scan_phase2(const int* __restrict__ block_sums,
                                                   int* __restrict__ block_off,
                                                   int* __restrict__ row_ptr,
                                                   int B, int N) {
    __shared__ int s[256];
    int t = threadIdx.x;
    int v = (t < B) ? block_sums[t] : 0;
    s[t] = v;
    __syncthreads();
#pragma unroll
    for (int off = 1; off < 256; off <<= 1) {
        int u = (t >= off) ? s[t - off] : 0;
        __syncthreads();
        s[t] += u;
        __syncthreads();
    }
    if (t < B) block_off[t] = s[t] - v;
    if (t == 255) row_ptr[N] = s[255];
}

__global__ __launch_bounds__(256) void scan_phase3(const int* __restrict__ deg,
                                                   const int* __restrict__ block_off,
                                                   int* __restrict__ row_ptr,
                                                   float* __restrict__ dis, int N) {
    int b = blockIdx.x, t = threadIdx.x;
    int base = b * 2048 + t * 8;
    const int4* p = reinterpret_cast<const int4*>(deg + base);
    int4 a = p[0], c = p[1];
    int d[8] = {a.x, a.y, a.z, a.w, c.x, c.y, c.z, c.w};
    int pre[8], s = 0;
#pragma unroll
    for (int j = 0; j < 8; ++j) { pre[j] = s; s += d[j]; }
    __shared__ int ls[256];
    ls[t] = s;
    __syncthreads();
#pragma unroll
    for (int off = 1; off < 256; off <<= 1) {
        int u = (t >= off) ? ls[t - off] : 0;
        __syncthreads();
        ls[t] += u;
        __syncthreads();
    }
    int excl = ls[t] - s + block_off[b];
#pragma unroll
    for (int j = 0; j < 8; ++j) {
        int i = base + j;
        if (i < N) {
            row_ptr[i] = excl + pre[j];
            dis[i] = rsqrtf((float)(d[j] + 1));
        }
    }
}

__global__ __launch_bounds__(256) void fill_csr(const int* __restrict__ src,
                                                const int* __restrict__ dst,
                                                const int* __restrict__ row_ptr,
                                                int* __restrict__ cnt,
                                                int* __restrict__ csr_src, int E) {
    int e = blockIdx.x * 256 + threadIdx.x;
    if (e < E) {
        int d = dst[e];
        int pos = row_ptr[d] + atomicAdd(&cnt[d], 1);
        csr_src[pos] = src[e];
    }
}

// ---------------- helpers ----------------

__device__ __forceinline__ ushort r16(float f) {
    __hip_bfloat16 h = __float2bfloat16(f);   // round-to-nearest-even
    return *reinterpret_cast<ushort*>(&h);
}
__device__ __forceinline__ float bf_lo(unsigned u) {   // feature 2f (low ushort)
    return __builtin_bit_cast(float, u << 16);
}
__device__ __forceinline__ float bf_hi(unsigned u) {   // feature 2f+1
    return __builtin_bit_cast(float, u & 0xFFFF0000u);
}

// ---------------- GEMM, row-scale + bf16 epilogue ----------------
// G16[r][c] = bf16( dis[r] * sum_k A[r][k] * W[k][c] )
template <int K, int DOUT>
__global__ __launch_bounds__(256) void gemm_scale(const float* __restrict__ A,
                                                  const float* __restrict__ W,
                                                  const float* __restrict__ dis,
                                                  ushort* __restrict__ G16, int N) {
    constexpr int CG   = DOUT / 4;
    constexpr int RG   = 256 / CG;
    constexpr int ROWS = RG * 4;
    constexpr int LDA  = K + 1;

    __shared__ __align__(16) float a_lds[ROWS * LDA];
    __shared__ __align__(16) float w_lds[K * DOUT];

    int t    = threadIdx.x;
    int row0 = blockIdx.x * ROWS;

    constexpr int WF4 = K * DOUT / 4;
    for (int q = t; q < WF4; q += 256)
        reinterpret_cast<float4*>(w_lds)[q] =
            reinterpret_cast<const float4*>(W)[q];

    constexpr int AF4 = ROWS * K / 4;
    for (int q = t; q < AF4; q += 256) {
        int r  = q / (K / 4);
        int kc = q % (K / 4);
        float4 v = make_float4(0.f, 0.f, 0.f, 0.f);
        int gr = row0 + r;
        if (gr < N)
            v = reinterpret_cast<const float4*>(A + (size_t)gr * K)[kc];
        float* p = &a_lds[r * LDA + kc * 4];
        p[0] = v.x; p[1] = v.y; p[2] = v.z; p[3] = v.w;
    }
    __syncthreads();

    int c0 = (t % CG) * 4;
    int r0 = (t / CG) * 4;

    float4 acc[4] = {};
#pragma unroll 4
    for (int k = 0; k < K; ++k) {
        float4 w4 = *reinterpret_cast<const float4*>(&w_lds[k * DOUT + c0]);
#pragma unroll
        for (int j = 0; j < 4; ++j) {
            float a = a_lds[(r0 + j) * LDA + k];
            acc[j].x += a * w4.x;
            acc[j].y += a * w4.y;
            acc[j].z += a * w4.z;
            acc[j].w += a * w4.w;
        }
    }

#pragma unroll
    for (int j = 0; j < 4; ++j) {
        int gr = row0 + r0 + j;
        if (gr < N) {
            float s = dis[gr];
            float4 o = acc[j];
            ushort4 pk;
            pk.x = r16(o.x * s); pk.y = r16(o.y * s);
            pk.z = r16(o.z * s); pk.w = r16(o.w * s);
            *reinterpret_cast<ushort4*>(&G16[(size_t)gr * DOUT + c0]) = pk;
        }
    }
}

// ---------------- GEMM, bias epilogue, fp32 out (final layer) ----------------
template <int K, int DOUT>
__global__ __launch_bounds__(256) void gemm_bias(const float* __restrict__ A,
                                                 const float* __restrict__ W,
                                                 const float* __restrict__ bias,
                                                 float* __restrict__ Out, int N) {
    constexpr int CG   = DOUT / 4;
    constexpr int RG   = 256 / CG;
    constexpr int ROWS = RG * 4;
    constexpr int LDA  = K + 1;

    __shared__ __align__(16) float a_lds[ROWS * LDA];
    __shared__ __align__(16) float w_lds[K * DOUT];

    int t    = threadIdx.x;
    int row0 = blockIdx.x * ROWS;

    constexpr int WF4 = K * DOUT / 4;
    for (int q = t; q < WF4; q += 256)
        reinterpret_cast<float4*>(w_lds)[q] =
            reinterpret_cast<const float4*>(W)[q];

    constexpr int AF4 = ROWS * K / 4;
    for (int q = t; q < AF4; q += 256) {
        int r  = q / (K / 4);
        int kc = q % (K / 4);
        float4 v = make_float4(0.f, 0.f, 0.f, 0.f);
        int gr = row0 + r;
        if (gr < N)
            v = reinterpret_cast<const float4*>(A + (size_t)gr * K)[kc];
        float* p = &a_lds[r * LDA + kc * 4];
        p[0] = v.x; p[1] = v.y; p[2] = v.z; p[3] = v.w;
    }
    __syncthreads();

    int c0 = (t % CG) * 4;
    int r0 = (t / CG) * 4;

    float4 acc[4] = {};
#pragma unroll 4
    for (int k = 0; k < K; ++k) {
        float4 w4 = *reinterpret_cast<const float4*>(&w_lds[k * DOUT + c0]);
#pragma unroll
        for (int j = 0; j < 4; ++j) {
            float a = a_lds[(r0 + j) * LDA + k];
            acc[j].x += a * w4.x;
            acc[j].y += a * w4.y;
            acc[j].z += a * w4.z;
            acc[j].w += a * w4.w;
        }
    }

    float4 b4v = *reinterpret_cast<const float4*>(&bias[c0]);
#pragma unroll
    for (int j = 0; j < 4; ++j) {
        int gr = row0 + r0 + j;
        if (gr < N) {
            float4 o = acc[j];
            o.x += b4v.x; o.y += b4v.y; o.z += b4v.z; o.w += b4v.w;
            reinterpret_cast<float4*>(Out + (size_t)gr * DOUT)[c0 / 4] = o;
        }
    }
}

// ---------------- Aggregation (half-wave uint gathers, D=64) ----------------
// Wave splits into 2 halves; each half gathers a DIFFERENT edge's 128 B row
// (32 lanes x uint = one row). 8-deep unroll = 16 edges in flight per wave.
// v = dis[n] * (G[n] + sum_src G[src]) [+ bias] [relu]
// OUT16: store bf16(dis[n]*v) pairs (table for next agg); else store fp32 v.
template <bool RELU, bool OUT16, bool BIAS>
__global__ __launch_bounds__(256) void aggregate_bf64(const unsigned* __restrict__ G,
                                                      const int* __restrict__ row_ptr,
                                                      const int* __restrict__ csr_src,
                                                      const float* __restrict__ dis,
                                                      const float* __restrict__ bias,
                                                      void* __restrict__ OutV, int N) {
    int wave = threadIdx.x >> 6;
    int lane = threadIdx.x & 63;
    int n = blockIdx.x * 4 + wave;
    if (n >= N) return;

    int h  = lane >> 5;        // which half-wave (edge parity)
    int fl = lane & 31;        // feature pair index

    int beg = row_ptr[n];
    int len = row_ptr[n + 1] - beg;
    int cnt = (len - h + 1) >> 1;              // my half's edge count
    const int* ep = csr_src + beg + h;         // my half's edges: ep[2k]

    float lo0 = 0.f, lo1 = 0.f, lo2 = 0.f, lo3 = 0.f;
    float hi0 = 0.f, hi1 = 0.f, hi2 = 0.f, hi3 = 0.f;

    int k = 0;
    for (; k + 8 <= cnt; k += 8) {
        int s0 = ep[2 * k],      s1 = ep[2 * k + 2];
        int s2 = ep[2 * k + 4],  s3 = ep[2 * k + 6];
        int s4 = ep[2 * k + 8],  s5 = ep[2 * k + 10];
        int s6 = ep[2 * k + 12], s7 = ep[2 * k + 14];
        unsigned u0 = G[(size_t)s0 * 32 + fl];
        unsigned u1 = G[(size_t)s1 * 32 + fl];
        unsigned u2 = G[(size_t)s2 * 32 + fl];
        unsigned u3 = G[(size_t)s3 * 32 + fl];
        unsigned u4 = G[(size_t)s4 * 32 + fl];
        unsigned u5 = G[(size_t)s5 * 32 + fl];
        unsigned u6 = G[(size_t)s6 * 32 + fl];
        unsigned u7 = G[(size_t)s7 * 32 + fl];
        lo0 += bf_lo(u0) + bf_lo(u4);  hi0 += bf_hi(u0) + bf_hi(u4);
        lo1 += bf_lo(u1) + bf_lo(u5);  hi1 += bf_hi(u1) + bf_hi(u5);
        lo2 += bf_lo(u2) + bf_lo(u6);  hi2 += bf_hi(u2) + bf_hi(u6);
        lo3 += bf_lo(u3) + bf_lo(u7);  hi3 += bf_hi(u3) + bf_hi(u7);
    }
    for (; k + 4 <= cnt; k += 4) {
        int s0 = ep[2 * k],     s1 = ep[2 * k + 2];
        int s2 = ep[2 * k + 4], s3 = ep[2 * k + 6];
        unsigned u0 = G[(size_t)s0 * 32 + fl];
        unsigned u1 = G[(size_t)s1 * 32 + fl];
        unsigned u2 = G[(size_t)s2 * 32 + fl];
        unsigned u3 = G[(size_t)s3 * 32 + fl];
        lo0 += bf_lo(u0);  hi0 += bf_hi(u0);
        lo1 += bf_lo(u1);  hi1 += bf_hi(u1);
        lo2 += bf_lo(u2);  hi2 += bf_hi(u2);
        lo3 += bf_lo(u3);  hi3 += bf_hi(u3);
    }
    for (; k < cnt; ++k) {
        unsigned u = G[(size_t)ep[2 * k] * 32 + fl];
        lo1 += bf_lo(u);  hi1 += bf_hi(u);
    }

    float lo = (lo0 + lo1) + (lo2 + lo3);
    float hi = (hi0 + hi1) + (hi2 + hi3);
    lo += __shfl_xor(lo, 32);   // combine the two halves
    hi += __shfl_xor(hi, 32);

    if (h == 0) {
        unsigned us = G[(size_t)n * 32 + fl];   // self-loop pair
        float dn = dis[n];
        float vlo = dn * (lo + bf_lo(us));
        float vhi = dn * (hi + bf_hi(us));
        if (BIAS) {
            float2 b2 = reinterpret_cast<const float2*>(bias)[fl];
            vlo += b2.x;  vhi += b2.y;
        }
        if (RELU) { vlo = fmaxf(vlo, 0.f); vhi = fmaxf(vhi, 0.f); }
        if (OUT16) {
            // NOTE the extra dn factor: s3 = bf16(dis[n] * v) for the
            // reassociated layer-4 aggregation. (R6 bug: factor was missing.)
            unsigned pk = (unsigned)r16(dn * vlo) | ((unsigned)r16(dn * vhi) << 16);
            ((unsigned*)OutV)[(size_t)n * 32 + fl] = pk;
        } else {
            reinterpret_cast<float2*>(OutV)[(size_t)n * 32 + fl] =
                make_float2(vlo, vhi);
        }
    }
}

// ---------------- Launch ----------------

extern "C" void kernel_launch(void* const* d_in, const int* in_sizes, int n_in,
                              void* d_out, int out_size, void* d_ws, size_t ws_size,
                              hipStream_t stream) {
    const float* x     = (const float*)d_in[0];
    const int*   edges = (const int*)d_in[1];   // [2, E] row-major
    const float* W1 = (const float*)d_in[2];
    const float* b1 = (const float*)d_in[3];
    const float* W2 = (const float*)d_in[4];
    const float* b2 = (const float*)d_in[5];
    const float* W3 = (const float*)d_in[6];
    const float* b3 = (const float*)d_in[7];
    const float* W4 = (const float*)d_in[8];
    const float* b4 = (const float*)d_in[9];

    const int DIN = 128, DH = 64;
    int N = in_sizes[0] / DIN;
    int E = in_sizes[1] / 2;

    const int* e_src = edges;
    const int* e_dst = edges + E;

    float* out   = (float*)d_out;
    float* x_hat = out;                       // [N,128]
    float* z     = out + (size_t)N * DIN;     // [N,64]

    int B    = (N + 2047) / 2048;
    int Npad = B * 2048;

    char*  ws  = (char*)d_ws;
    size_t off = 0;
    auto carve = [&](size_t bytes) {
        void* p = ws + off;
        off = (off + bytes + 255) & ~(size_t)255;
        return p;
    };
    float*  dis        = (float*) carve((size_t)N * 4);
    int*    deg        = (int*)   carve((size_t)Npad * 4);
    int*    cnt        = (int*)   carve((size_t)N * 4);
    int*    row_ptr    = (int*)   carve((size_t)(N + 1) * 4);
    int*    csr_src    = (int*)   carve((size_t)E * 4);
    int*    block_sums = (int*)   carve((size_t)B * 4);
    int*    block_off  = (int*)   carve((size_t)B * 4);
    ushort* g16        = (ushort*)carve((size_t)N * DH * 2);   // gather table
    ushort* s3         = (ushort*)carve((size_t)N * DH * 2);   // layer-3 scaled out
    float*  t          = (float*) carve((size_t)N * DH * 4);   // layer-4 agg result
    float*  act        = (float*) carve((size_t)N * DH * 4);   // h (layer-1 out)
    (void)ws_size;

    int nb_e   = (E + 255) / 256;
    int nb_agg = (N + 3) / 4;

    // CSR build
    init_k<<<(Npad + 255) / 256, 256, 0, stream>>>(deg, cnt, Npad, N);
    hist_deg<<<nb_e, 256, 0, stream>>>(e_dst, deg, E);
    scan_phase1<<<B, 256, 0, stream>>>(deg, block_sums);
    scan_phase2<<<1, 256, 0, stream>>>(block_sums, block_off, row_ptr, B, N);
    scan_phase3<<<B, 256, 0, stream>>>(deg, block_off, row_ptr, dis, N);
    fill_csr<<<nb_e, 256, 0, stream>>>(e_src, e_dst, row_ptr, cnt, csr_src, E);

    // Layer 1: h = relu(dis*(sum g1)+b1), g1 = dis*(x W1)
    gemm_scale<128, 64><<<(N + 63) / 64, 256, 0, stream>>>(x, W1, dis, g16, N);
    aggregate_bf64<true, false, true><<<nb_agg, 256, 0, stream>>>(
        (const unsigned*)g16, row_ptr, csr_src, dis, b1, act, N);

    // Layer 2: z = relu(...) -> d_out (fp32)
    gemm_scale<64, 64><<<(N + 63) / 64, 256, 0, stream>>>(act, W2, dis, g16, N);
    aggregate_bf64<true, false, true><<<nb_agg, 256, 0, stream>>>(
        (const unsigned*)g16, row_ptr, csr_src, dis, b2, z, N);

    // Layer 3: s3 = bf16(dis * relu(...))  (table for layer-4 aggregation)
    gemm_scale<64, 64><<<(N + 63) / 64, 256, 0, stream>>>(z, W3, dis, g16, N);
    aggregate_bf64<true, true, true><<<nb_agg, 256, 0, stream>>>(
        (const unsigned*)g16, row_ptr, csr_src, dis, b3, s3, N);

    // Layer 4 (reassociated): t = dis*(s3[n] + sum s3[src]);  x_hat = t W4 + b4
    aggregate_bf64<false, false, false><<<nb_agg, 256, 0, stream>>>(
        (const unsigned*)s3, row_ptr, csr_src, dis, nullptr, t, N);
    gemm_bias<64, 128><<<(N + 31) / 32, 256, 0, stream>>>(t, W4, b4, x_hat, N);
}